// Round 1
// baseline (182.295 us; speedup 1.0000x reference)
//
#include <hip/hip_runtime.h>

// Idealizer: torsion angles + backbone frames -> atom14 coordinates.
// One thread per residue. Tables staged in LDS. Group-scatter placement
// (walk groups 0..7, predicated-accumulate matching atoms) to avoid
// dynamic register-array indexing.

struct F3 { float x, y, z; };

__device__ __forceinline__ F3 f3sub(F3 a, F3 b) { return {a.x-b.x, a.y-b.y, a.z-b.z}; }
__device__ __forceinline__ F3 f3cross(F3 a, F3 b) {
    return {a.y*b.z - a.z*b.y, a.z*b.x - a.x*b.z, a.x*b.y - a.y*b.x};
}
__device__ __forceinline__ float f3dot(F3 a, F3 b) { return a.x*b.x + a.y*b.y + a.z*b.z; }

// sin/cos of the dihedral angle directly (reference takes sincos(atan2(y,x))).
__device__ __forceinline__ void dihedral_sc(F3 p0, F3 p1, F3 p2, F3 p3,
                                            float& s, float& c) {
    F3 b0 = f3sub(p0, p1);          // -(p1 - p0)
    F3 b1 = f3sub(p2, p1);
    F3 b2 = f3sub(p3, p2);
    F3 u = f3cross(b0, b1);         // b0 x b1
    F3 v = f3cross(b2, b1);         // named b1xb2 in ref but is cross(b2, b1)
    F3 w = f3cross(u, v);
    float y = f3dot(w, b1) * rsqrtf(fmaxf(f3dot(b1, b1), 1e-30f));
    float x = f3dot(u, v);
    float r2 = x*x + y*y;
    if (r2 > 1e-24f) {
        float rinv = rsqrtf(r2);
        s = y * rinv;
        c = x * rinv;
    } else {                        // atan2(0,0)=0 / nan_to_num -> angle 0
        s = 0.0f;
        c = 1.0f;
    }
}

#define DF_STRIDE 132   // 128 + 4 pad: spreads per-aa LDS rows across banks

__global__ __launch_bounds__(256) void idealizer_kernel(
    const int*   __restrict__ aa,       // (n,)
    const float* __restrict__ bb,       // (n,4,3)
    const float* __restrict__ tor,      // (n,4)
    const float* __restrict__ dframes,  // (21,8,4,4)
    const int*   __restrict__ gidx,     // (21,14)
    const float* __restrict__ amask,    // (21,14)
    const float* __restrict__ lit,      // (21,14,3)
    float*       __restrict__ out,      // (n,14,3)
    int n)
{
    __shared__ float s_df[21 * DF_STRIDE];
    __shared__ float s_lit[21 * 14 * 3];
    __shared__ float s_mask[21 * 14];
    __shared__ int   s_g[21 * 14];

    const int tid = threadIdx.x;
    for (int j = tid; j < 21 * 128; j += 256) {
        int a = j >> 7, r = j & 127;
        s_df[a * DF_STRIDE + r] = dframes[j];
    }
    for (int j = tid; j < 21 * 14 * 3; j += 256) s_lit[j] = lit[j];
    for (int j = tid; j < 21 * 14; j += 256) { s_mask[j] = amask[j]; s_g[j] = gidx[j]; }
    __syncthreads();

    const int i = blockIdx.x * 256 + tid;
    if (i >= n) return;

    // ---- load own residue backbone (12 floats) ----
    const float4* bb4 = (const float4*)bb;
    float4 q0 = bb4[i * 3 + 0];   // N.xyz, CA.x
    float4 q1 = bb4[i * 3 + 1];   // CA.yz, C.xy
    float4 q2 = bb4[i * 3 + 2];   // C.z, atom3.xyz
    F3 Np  = {q0.x, q0.y, q0.z};
    F3 CAp = {q0.w, q1.x, q1.y};
    F3 Cp  = {q1.z, q1.w, q2.x};

    // ---- neighbors (clamped; boundary angles overridden below) ----
    const int im = (i > 0)     ? i - 1 : 0;
    const int ip = (i < n - 1) ? i + 1 : 0;
    F3 Cm = { bb[im * 12 + 6], bb[im * 12 + 7], bb[im * 12 + 8] };   // C[i-1]
    float4 r0 = bb4[ip * 3 + 0];                                      // N[i+1], CA[i+1].x
    float2 r1 = ((const float2*)bb)[ip * 6 + 2];                      // CA[i+1].yz
    F3 Nn  = {r0.x, r0.y, r0.z};
    F3 CAn = {r0.w, r1.x, r1.y};

    // ---- backbone dihedrals (sin/cos directly) ----
    float s_ph, c_ph, s_ps, c_ps, s_om, c_om;
    dihedral_sc(Cm,  Np,  CAp, Cp,  s_ph, c_ph);   // phi  = D(C[i-1],N,CA,C)
    dihedral_sc(Np,  CAp, Cp,  Nn,  s_ps, c_ps);   // psi  = D(N,CA,C,N[i+1])
    dihedral_sc(CAp, Cp,  Nn,  CAn, s_om, c_om);   // omega= D(CA,C,N[i+1],CA[i+1])
    if (i == 0)     { s_ph = 0.0f; c_ph = 1.0f; }
    if (i == n - 1) { s_ps = 0.0f; c_ps = 1.0f; s_om = 0.0f; c_om = 1.0f; }

    // ---- backbone frame from reference (N, CA, C) ----
    const float eps = 1e-20f;
    F3 nv = f3sub(Np, CAp);
    F3 cv = f3sub(Cp, CAp);
    float cx = cv.x, cy = cv.y, cz = cv.z;
    float d2xy  = cx * cx + cy * cy;
    float inrm  = rsqrtf(eps + d2xy);
    float s1 = -cy * inrm, c1 = cx * inrm;
    float inrm2 = rsqrtf(eps + d2xy + cz * cz);
    float s2 = cz * inrm2, c2 = sqrtf(d2xy) * inrm2;
    // Rc = R2 @ R1
    float Rc00 = c2 * c1,  Rc01 = -c2 * s1, Rc02 = s2;
    float Rc10 = s1,       Rc11 = c1,       Rc12 = 0.0f;
    float Rc20 = -s2 * c1, Rc21 = s2 * s1,  Rc22 = c2;
    float n2y = Rc10 * nv.x + Rc11 * nv.y + Rc12 * nv.z;
    float n2z = Rc20 * nv.x + Rc21 * nv.y + Rc22 * nv.z;
    float inrm3 = rsqrtf(eps + n2y * n2y + n2z * n2z);
    float sn = -n2z * inrm3, cn = n2y * inrm3;
    // M = Rn @ Rc ; bb_r = M^T
    float M10 = cn * Rc10 - sn * Rc20, M11 = cn * Rc11 - sn * Rc21, M12 = cn * Rc12 - sn * Rc22;
    float M20 = sn * Rc10 + cn * Rc20, M21 = sn * Rc11 + cn * Rc21, M22 = sn * Rc12 + cn * Rc22;
    float B00 = Rc00, B01 = M10, B02 = M20;
    float B10 = Rc01, B11 = M11, B12 = M21;
    float B20 = Rc02, B21 = M12, B22 = M22;
    // bb_t = CA

    // ---- per-frame sin/cos: [identity, omega, phi, psi, tor0..3] ----
    float4 tv = ((const float4*)tor)[i];
    float sang[8], cang[8];
    sang[0] = 0.0f; cang[0] = 1.0f;
    sang[1] = s_om; cang[1] = c_om;
    sang[2] = s_ph; cang[2] = c_ph;
    sang[3] = s_ps; cang[3] = c_ps;
    __sincosf(tv.x, &sang[4], &cang[4]);
    __sincosf(tv.y, &sang[5], &cang[5]);
    __sincosf(tv.z, &sang[6], &cang[6]);
    __sincosf(tv.w, &sang[7], &cang[7]);

    // ---- write backbone passthrough (atoms 0..3) ----
    float2* o2 = (float2*)(out + (size_t)i * 42);
    o2[0] = make_float2(q0.x, q0.y);
    o2[1] = make_float2(q0.z, q0.w);
    o2[2] = make_float2(q1.x, q1.y);
    o2[3] = make_float2(q1.z, q1.w);
    o2[4] = make_float2(q2.x, q2.y);
    o2[5] = make_float2(q2.z, q2.w);

    // ---- hoist per-atom tables (atoms 4..13) ----
    const int aai = aa[i];
    const int tb  = aai * 14;
    int   ga[10];
    float ma[10], lx[10], ly[10], lz[10];
    #pragma unroll
    for (int a = 0; a < 10; a++) {
        int t = tb + 4 + a;
        ga[a] = s_g[t];
        ma[a] = s_mask[t];
        int lo = t * 3;
        lx[a] = s_lit[lo]; ly[a] = s_lit[lo + 1]; lz[a] = s_lit[lo + 2];
    }
    float axv[10], ayv[10], azv[10];
    #pragma unroll
    for (int a = 0; a < 10; a++) { axv[a] = 0.0f; ayv[a] = 0.0f; azv[a] = 0.0f; }

    // ---- group chain: cur = global frame of group g ----
    float G00, G01, G02, G10, G11, G12, G20, G21, G22, Gx, Gy, Gz;
    const int dbase = aai * DF_STRIDE;
    #pragma unroll
    for (int g = 0; g < 8; g++) {
        // default frame rows (dr | dt) for this group
        const float4* dfr = (const float4*)&s_df[dbase + g * 16];
        float4 d0 = dfr[0], d1 = dfr[1], d2 = dfr[2];
        float sA = sang[g], cA = cang[g];
        // fr = dr @ Ra(angle): col0 = dr col0; col1 = c*c1+s*c2; col2 = c*c2-s*c1
        float f00 = d0.x, f01 = cA * d0.y + sA * d0.z, f02 = cA * d0.z - sA * d0.y;
        float f10 = d1.x, f11 = cA * d1.y + sA * d1.z, f12 = cA * d1.z - sA * d1.y;
        float f20 = d2.x, f21 = cA * d2.y + sA * d2.z, f22 = cA * d2.z - sA * d2.y;
        // base frame: groups 0..4 compose with backbone; 5..7 chain off previous
        float A00, A01, A02, A10, A11, A12, A20, A21, A22, Atx, Aty, Atz;
        if (g <= 4) {
            A00 = B00; A01 = B01; A02 = B02;
            A10 = B10; A11 = B11; A12 = B12;
            A20 = B20; A21 = B21; A22 = B22;
            Atx = CAp.x; Aty = CAp.y; Atz = CAp.z;
        } else {
            A00 = G00; A01 = G01; A02 = G02;
            A10 = G10; A11 = G11; A12 = G12;
            A20 = G20; A21 = G21; A22 = G22;
            Atx = Gx; Aty = Gy; Atz = Gz;
        }
        // G = A @ fr ; Gt = A . dt + At
        float n00 = A00 * f00 + A01 * f10 + A02 * f20;
        float n01 = A00 * f01 + A01 * f11 + A02 * f21;
        float n02 = A00 * f02 + A01 * f12 + A02 * f22;
        float n10 = A10 * f00 + A11 * f10 + A12 * f20;
        float n11 = A10 * f01 + A11 * f11 + A12 * f21;
        float n12 = A10 * f02 + A11 * f12 + A12 * f22;
        float n20 = A20 * f00 + A21 * f10 + A22 * f20;
        float n21 = A20 * f01 + A21 * f11 + A22 * f21;
        float n22 = A20 * f02 + A21 * f12 + A22 * f22;
        float ntx = A00 * d0.w + A01 * d1.w + A02 * d2.w + Atx;
        float nty = A10 * d0.w + A11 * d1.w + A12 * d2.w + Aty;
        float ntz = A20 * d0.w + A21 * d1.w + A22 * d2.w + Atz;
        G00 = n00; G01 = n01; G02 = n02;
        G10 = n10; G11 = n11; G12 = n12;
        G20 = n20; G21 = n21; G22 = n22;
        Gx = ntx; Gy = nty; Gz = ntz;

        // predicated accumulate for atoms whose group matches g
        #pragma unroll
        for (int a = 0; a < 10; a++) {
            float m = (ga[a] == g) ? ma[a] : 0.0f;
            float px = G00 * lx[a] + G01 * ly[a] + G02 * lz[a] + Gx;
            float py = G10 * lx[a] + G11 * ly[a] + G12 * lz[a] + Gy;
            float pz = G20 * lx[a] + G21 * ly[a] + G22 * lz[a] + Gz;
            axv[a] = fmaf(m, px, axv[a]);
            ayv[a] = fmaf(m, py, ayv[a]);
            azv[a] = fmaf(m, pz, azv[a]);
        }
    }

    // ---- store atoms 4..13 (floats 12..41 of the row) ----
    float v[30];
    #pragma unroll
    for (int a = 0; a < 10; a++) {
        v[3 * a] = axv[a]; v[3 * a + 1] = ayv[a]; v[3 * a + 2] = azv[a];
    }
    #pragma unroll
    for (int k = 0; k < 15; k++) {
        o2[6 + k] = make_float2(v[2 * k], v[2 * k + 1]);
    }
}

extern "C" void kernel_launch(void* const* d_in, const int* in_sizes, int n_in,
                              void* d_out, int out_size, void* d_ws, size_t ws_size,
                              hipStream_t stream) {
    const int*   aa  = (const int*)d_in[0];
    const float* bb  = (const float*)d_in[1];
    const float* tor = (const float*)d_in[2];
    const float* df  = (const float*)d_in[3];
    const int*   gi  = (const int*)d_in[4];
    const float* am  = (const float*)d_in[5];
    const float* lp  = (const float*)d_in[6];
    float* outp = (float*)d_out;
    const int n = in_sizes[0];
    const int blocks = (n + 255) / 256;
    idealizer_kernel<<<blocks, 256, 0, stream>>>(aa, bb, tor, df, gi, am, lp, outp, n);
}